// Round 1
// 1121.670 us; speedup vs baseline: 1.2758x; 1.2758x over previous
//
#include <hip/hip_runtime.h>

// ---------------------------------------------------------------------------
// 3-state pair-HMM forward DP (logsumexp semiring), skewed band pipeline.
//   24 bands x 64 rows, one 64-lane wave per band. Lane r owns row 64b+r+1,
//   at step t computes column j = (t - r) + 1. up/diag flow via __shfl_up.
//   Band handoff through global `bottom` rows + agent-scope progress flags.
// R5: R3/R4 measured ~900 cy/column == one load latency per column. The
//   compiler sank the "prefetch" memcpy loads to their uses both times
//   (VGPR_Count 136 < the 144 floats of the theta double buffer), so
//   sched_barrier alone does not pin them. This round the pipeline is made
//   uncheatable: all prefetch loads are inline-asm global_load into named
//   registers, issued ONE BLOCK (8 columns) ahead, consumed after a single
//   hand-counted s_waitcnt per block (vmcnt retires in order; the count
//   equals the VMEM ops issued after the waited-on loads = this band's
//   16 bottom-row stores, which are also inline-asm so the count is
//   deterministic -- inactive columns store to the never-read slot j=0).
//   Expected: ~900 -> ~200 cy/column, VGPR ~240.
// ---------------------------------------------------------------------------

#define MM 1536
#define HH 64
#define NB 24
#define U  8
#define NBLK 200                    // 200*8 = 1600 >= MM+HH-1 = 1599 steps
#define LOG2E 1.4426950408889634f
#define LN2   0.6931471805599453f
#define NEG2  (-1.4426950408889634e8f)   // (-1e8) * LOG2E (log2-domain -inf)

typedef float f32x4 __attribute__((ext_vector_type(4)));
typedef float f32x2 __attribute__((ext_vector_type(2)));

struct T9R { f32x4 q0; f32x4 q1; float s8; };   // theta[c][0..8]
struct F3R { f32x2 d01; float d2; };            // bottom-row feed (3 floats)

__device__ __forceinline__ float lse3_2(float a, float b, float c) {
    // log2-domain LSE of 3: max3 + med3 + min3 (hw ops), 2 exp2 + 1 log2.
    float mx = fmaxf(fmaxf(a, b), c);
    float mn = fminf(fminf(a, b), c);
    float md = __builtin_amdgcn_fmed3f(a, b, c);
    return mx + __builtin_amdgcn_logf(1.0f + __builtin_amdgcn_exp2f(mn - mx)
                                           + __builtin_amdgcn_exp2f(md - mx));
}

__global__ void init_progress_kernel(int* progress) {
    if (threadIdx.x < NB) progress[threadIdx.x] = -1;
}

__global__ __launch_bounds__(64, 1)
void hmm_fwd_kernel(const float* __restrict__ theta, float* __restrict__ out,
                    float* __restrict__ bottom, int* __restrict__ progress)
{
    const int b    = blockIdx.x;
    const int lane = threadIdx.x;
    const float* __restrict__ thp = theta + (size_t)(b * HH + lane) * (MM * 9);
    const float* __restrict__ bsrc =
        bottom + (size_t)(b > 0 ? b - 1 : 0) * ((MM + 1) * 3);
    float* __restrict__ bdst = bottom + (size_t)b * ((MM + 1) * 3);

    T9R thA[U], thB[U];      // theta double buffer, inline-asm loaded
    F3R fdA[U], fdB[U];      // lane-0 'up' feed double buffer

    float d0, d1, d2, l0, l1, l2, s0, s1, s2, res0, res1, res2;
    d0 = d1 = d2 = (b == 0 && lane == 0) ? 0.0f : NEG2;   // V[0,0] = 0 border
    l0 = l1 = l2 = NEG2;
    s0 = s1 = s2 = NEG2;
    res0 = res1 = res2 = NEG2;

    #pragma unroll
    for (int k = 0; k < U; ++k) {
        fdA[k].d01.x = NEG2; fdA[k].d01.y = NEG2; fdA[k].d2 = NEG2;
        fdB[k].d01.x = NEG2; fdB[k].d01.y = NEG2; fdB[k].d2 = NEG2;
    }

    // ---- inline-asm load issue helpers (volatile => compiler cannot sink,
    //      reorder, or re-materialize these; registers stay resident) ----
    auto issue_theta = [&](int tb, T9R (&buf)[U]) {
        #pragma unroll
        for (int k = 0; k < U; ++k) {
            int c = tb + k - lane;
            c = c < 0 ? 0 : (c > MM - 1 ? MM - 1 : c);   // clamp addr; value
            const float* a = thp + (size_t)c * 9;        // unused when !act
            asm volatile("global_load_dwordx4 %0, %1, off"
                         : "=v"(buf[k].q0) : "v"(a));
            asm volatile("global_load_dwordx4 %0, %1, off offset:16"
                         : "=v"(buf[k].q1) : "v"(a));
            asm volatile("global_load_dword %0, %1, off offset:32"
                         : "=v"(buf[k].s8) : "v"(a));
        }
    };
    auto issue_feed = [&](int tb, F3R (&buf)[U]) {
        #pragma unroll
        for (int k = 0; k < U; ++k) {
            int jn = tb + k + 1; if (jn > MM) jn = MM;
            const float* a = bsrc + (size_t)jn * 3;
            asm volatile("global_load_dwordx2 %0, %1, off"
                         : "=v"(buf[k].d01) : "v"(a));
            asm volatile("global_load_dword %0, %1, off offset:8"
                         : "=v"(buf[k].d2) : "v"(a));
        }
    };

    // pre-loop sync: covers prime (j<=8) + block-0 prefetch (j<=16) + block-1 (j<=24)
    if (b > 0) {
        while (__hip_atomic_load(&progress[b - 1], __ATOMIC_ACQUIRE,
                                 __HIP_MEMORY_SCOPE_AGENT) < 24)
            __builtin_amdgcn_s_sleep(2);
    }

    // prime block 0 into the A buffers; full drain once (only cold stall)
    issue_theta(0, thA);
    if (b > 0) issue_feed(0, fdA);
    asm volatile("s_waitcnt vmcnt(0)");
    __builtin_amdgcn_sched_barrier(0);

    auto block_body = [&](int T, T9R (&cur)[U], T9R (&nxt)[U],
                          F3R (&fcur)[U], F3R (&fnxt)[U]) {
        const int t0 = T * U;

        // consumer poll (even blocks): guarantee feed cols through t0+24
        if (b > 0 && T > 0 && (T & 1) == 0) {
            int need = t0 + 24; if (need > MM) need = MM;
            while (__hip_atomic_load(&progress[b - 1], __ATOMIC_ACQUIRE,
                                     __HIP_MEMORY_SCOPE_AGENT) < need)
                __builtin_amdgcn_s_sleep(2);
        }

        // Wait for cur (= L(T), issued one block ago). vmcnt retires in
        // order; worst-case queue here is [L(T), S(T-1)=16], so leaving 16
        // outstanding drains exactly all of L(T) without stalling on stores.
        // Band NB-1 issues no stores -> full drain (still zero-stall: the
        // loads are a whole block old).
        if (b < NB - 1) asm volatile("s_waitcnt vmcnt(16)");
        else            asm volatile("s_waitcnt vmcnt(0)");

        // issue block T+1 (stays in flight across the whole compute below)
        issue_theta(t0 + U, nxt);
        if (b > 0) issue_feed(t0 + U, fnxt);
        __builtin_amdgcn_sched_barrier(0);   // compute may not hoist above

        // compute 8 columns from the current (resident) buffers
        #pragma unroll
        for (int k = 0; k < U; ++k) {
            const int c = t0 + k - lane;
            const bool act = ((unsigned)c < (unsigned)MM);

            float u0 = (lane == 0) ? fcur[k].d01.x : s0;
            float u1 = (lane == 0) ? fcur[k].d01.y : s1;
            float u2 = (lane == 0) ? fcur[k].d2    : s2;

            float aa0 = fmaf(cur[k].q0.x, LOG2E, d0);
            float aa1 = fmaf(cur[k].q0.y, LOG2E, d1);
            float aa2 = fmaf(cur[k].q0.z, LOG2E, d2);
            float bb0 = fmaf(cur[k].q0.w, LOG2E, u0);
            float bb1 = fmaf(cur[k].q1.x, LOG2E, u1);
            float bb2 = fmaf(cur[k].q1.y, LOG2E, u2);
            float cc0 = fmaf(cur[k].q1.z, LOG2E, l0);
            float cc1 = fmaf(cur[k].q1.w, LOG2E, l1);
            float cc2 = fmaf(cur[k].s8,   LOG2E, l2);

            float n0 = lse3_2(aa0, aa1, aa2);
            float n1 = lse3_2(bb0, bb1, bb2);
            float n2 = lse3_2(cc0, cc1, cc2);
            n0 = act ? n0 : NEG2;
            n1 = act ? n1 : NEG2;
            n2 = act ? n2 : NEG2;

            // producer: lane 63 streams this band's bottom row. Inline-asm
            // stores with a DETERMINISTIC count (16/block): inactive columns
            // dump masked NEG2 into slot j=0, which no consumer ever reads
            // (feeds start at jn=1).
            if (b < NB - 1 && lane == HH - 1) {
                const int j = act ? c + 1 : 0;
                float* sa = bdst + (size_t)j * 3;
                f32x2 p01; p01.x = n0; p01.y = n1;
                asm volatile("global_store_dwordx2 %0, %1, off"
                             :: "v"(sa), "v"(p01) : "memory");
                asm volatile("global_store_dword %0, %1, off offset:8"
                             :: "v"(sa), "v"(n2) : "memory");
            }

            // capture V[N,M] (c == MM-1 on lane 63 of band NB-1)
            const bool fin = (c == MM - 1);
            res0 = fin ? n0 : res0;
            res1 = fin ? n1 : res1;
            res2 = fin ? n2 : res2;

            // rotate wavefront state
            d0 = u0; d1 = u1; d2 = u2;
            s0 = __shfl_up(n0, 1, 64);
            s1 = __shfl_up(n1, 1, 64);
            s2 = __shfl_up(n2, 1, 64);
            l0 = n0; l1 = n1; l2 = n2;
        }

        // publish progress every 2 blocks. Explicit vmcnt(0) first: release
        // visibility of the asm stores must not depend on the compiler
        // tracking them (it can't see inside the asm).
        if (b < NB - 1 && lane == HH - 1 && (T & 1) == 1) {
            int val = t0 - 55;                 // j_last = (t0+7) - 63 + 1
            if (val >= 1) {
                if (val > MM) val = MM;
                asm volatile("s_waitcnt vmcnt(0)");
                __hip_atomic_store(&progress[b], val, __ATOMIC_RELEASE,
                                   __HIP_MEMORY_SCOPE_AGENT);
            }
        }
    };

    for (int T2 = 0; T2 < NBLK; T2 += 2) {
        block_body(T2,     thA, thB, fdA, fdB);
        block_body(T2 + 1, thB, thA, fdB, fdA);
    }

    if (b == NB - 1 && lane == HH - 1)
        out[0] = LN2 * lse3_2(res0, res1, res2);
}

extern "C" void kernel_launch(void* const* d_in, const int* in_sizes, int n_in,
                              void* d_out, int out_size, void* d_ws, size_t ws_size,
                              hipStream_t stream)
{
    const float* theta = (const float*)d_in[0];
    float* out = (float*)d_out;

    float* bottom   = (float*)d_ws;                       // 24*1537*3 floats
    int*   progress = (int*)((char*)d_ws +
                             (size_t)NB * (MM + 1) * 3 * sizeof(float));

    init_progress_kernel<<<1, 64, 0, stream>>>(progress);
    hmm_fwd_kernel<<<NB, HH, 0, stream>>>(theta, out, bottom, progress);
}